// Round 17
// baseline (382.649 us; speedup 1.0000x reference)
//
#include <hip/hip_runtime.h>

// Problem constants
#define SRC    16384     // 128*128 source pixels
#define DCH    64        // channels
#define NCLS   19        // classes
#define NPAIR  (NCLS*DCH)// 1216 (c,d) pairs

// Bare v_exp_f32 via inline asm (proven). Args here are always <= 0;
// flush-to-zero on underflow matches reference f32 exp behavior.
__device__ __forceinline__ float exp2_raw(float x)
{
    float r;
    asm("v_exp_f32 %0, %1" : "=v"(r) : "v"(x));
    return r;
}

// ---------------------------------------------------------------------------
// K1: per-source-pixel class counts (proven). Also zeroes psum.
// ---------------------------------------------------------------------------
__global__ __launch_bounds__(256) void hl_count_kernel(
    const int* __restrict__ label, unsigned char* __restrict__ cnt,
    float* __restrict__ psum)
{
    if (blockIdx.x == 0 && threadIdx.x == 0) psum[0] = 0.f;
    int s  = blockIdx.x * 256 + threadIdx.x;   // 64 blocks x 256 = 16384
    int sy = s >> 7, sx = s & 127;
    const int4* lab4 = (const int4*)label;
    int l[16];
#pragma unroll
    for (int r = 0; r < 4; r++) {
        int4 v = lab4[(4 * sy + r) * 128 + sx];
        l[4 * r + 0] = v.x; l[4 * r + 1] = v.y;
        l[4 * r + 2] = v.z; l[4 * r + 3] = v.w;
    }
#pragma unroll
    for (int c = 0; c < NCLS; c++) {
        int cc = 0;
#pragma unroll
        for (int j = 0; j < 16; j++) cc += (l[j] == c) ? 1 : 0;
        cnt[c * SRC + s] = (unsigned char)cc;
    }
}

// ---------------------------------------------------------------------------
// K2: fused moments + KDE. One 256-thread block per (c,d), 64 px/thread.
// Pass 1: proven f64-reduced moments.
// Pass 2 (R15 post-mortem): the kernel is ISSUE-bound, not trans-bound.
//   Ledger (instr/el, LDSops/el, time): 7-exp reg = (31,0,43.8);
//   3-exp LDS-RMW = (20,15,44.5) -- 15x5.8cyc LDS-pipe = 44us, LDS-BOUND;
//   3-exp cndmask = (61,0,60.1) -- VALU-bound, VALUBusy 74%.
//   This version minimizes BOTH: 3-bin truncation (|o|>=2 terms <= e^{-28}
//   ~1e-11 vs hist O(1e2-1e3): invisible in f32) + direct args (no overflow
//   clamp needed: a = C1*(v+o)^2 <= 0 always, exp2 flushes to 0 safely) +
//   ds_add_f32 scatter: the NATIVE LDS float atomic-add instruction, emitted
//   via inline asm (compiler only emits CAS without unsafe-fp-atomics -- the
//   R7 533us disaster). 3 fire-and-forget LDS ops/el vs R10's 15.
//   Columns hist[slot][t] are thread-private (bank = t%32, free 2-way alias);
//   __syncthreads() fences init->accumulate->readback against asm motion.
//   Slot map: k0 = rint(clamp(u,-3,3)), slot = k0+3+oo, oo=0,1,2 for bins
//   k0-1,k0,k0+1; bin j lives at slot j+1; slots 0 and 8 are discards.
//   ~25 VALU + 3 trans + 3 LDS per element -> ~50 cyc/wave-el model.
// launch_bounds(256,4): proven no-spill budget.
// ---------------------------------------------------------------------------
__global__ __launch_bounds__(256, 4) void hl_fused_kernel(
    const float* __restrict__ feature, const unsigned char* __restrict__ cnt,
    int* __restrict__ ncls, float* __restrict__ psum)
{
    int w = blockIdx.x;             // pair 0..1215
    int c = w >> 6, d = w & 63;
    int t = threadIdx.x;
    int wid = t >> 6;

    const float4*       fp4 = (const float4*)(feature + d * SRC);
    const unsigned int* cpu = (const unsigned int*)(cnt + c * SRC);

    // ---- Pass 1: moments (proven) -----------------------------------------
    float f1 = 0.f, f2 = 0.f;
    int   nc = 0;
#pragma unroll 8
    for (int i = 0; i < 16; i++) {
        int g = i * 256 + t;        // 4096 float4-groups (= 4096 uint groups)
        float4       x  = fp4[g];
        unsigned int cv = cpu[g];
        float xs[4] = {x.x, x.y, x.z, x.w};
        float cf[4] = {(float)(cv & 255u), (float)((cv >> 8) & 255u),
                       (float)((cv >> 16) & 255u), (float)(cv >> 24)};
#pragma unroll
        for (int e = 0; e < 4; e++) {
            float wx = cf[e] * xs[e];
            f1 += wx;
            f2 = fmaf(wx, xs[e], f2);
        }
        nc += (cv & 255u) + ((cv >> 8) & 255u) + ((cv >> 16) & 255u) + (cv >> 24);
    }
    double s1 = (double)f1, s2 = (double)f2;
#pragma unroll
    for (int o = 32; o > 0; o >>= 1) {
        s1 += __shfl_down(s1, o);
        s2 += __shfl_down(s2, o);
        nc += __shfl_down(nc, o);
    }
    __shared__ float  hist[9][256];   // KDE histogram columns (pass 2)
    __shared__ double ps1[4], ps2[4];
    __shared__ int    pn[4];
    __shared__ float  sh_mu, sh_istd;
    __shared__ int    sh_act;
    if ((t & 63) == 0) { ps1[wid] = s1; ps2[wid] = s2; pn[wid] = nc; }
    __syncthreads();
    if (t == 0) {
        double a = ps1[0] + ps1[1] + ps1[2] + ps1[3];
        double b = ps2[0] + ps2[1] + ps2[2] + ps2[3];
        int    n = pn[0] + pn[1] + pn[2] + pn[3];
        double nsafe = (n > 0) ? (double)n : 1.0;
        double mu  = a / nsafe;
        double var = (b - 2.0 * mu * a + mu * mu * (double)n) / nsafe + 1e-10;
        sh_mu   = (float)mu;
        sh_istd = (float)(1.0 / sqrt(var));
        sh_act  = (n >= 1000);
        if (d == 0) ncls[c] = n;    // plain store; consumed only by K3
    }
    __syncthreads();
    if (!sh_act) return;            // inactive class: contributes 0
    float istd = sh_istd;
    float nm   = -sh_mu * istd;     // u = fma(x, istd, nm)

    // ---- Pass 2: KDE, 3-exp direct + ds_add_f32 scatter -------------------
    const float C1 = -18.033688011112042f;   // -12.5 * log2(e)

    // zero this thread's private histogram column
#pragma unroll
    for (int s9 = 0; s9 < 9; s9++) hist[s9][t] = 0.f;
    __syncthreads();                // fence: init complete before asm ds_adds

    // LDS byte address of &hist[3][t] (low-32 of flat shared addr = LDS
    // offset on gfx9+; shared-aperture base has zero low bits).
    unsigned Bcol = (unsigned)(unsigned long long)&hist[3][t];

#pragma unroll 2
    for (int i = 0; i < 16; i++) {
        int g = i * 256 + t;
        float4       x  = fp4[g];
        unsigned int cv = cpu[g];
        float xs[4] = {x.x, x.y, x.z, x.w};
        float cf[4] = {(float)(cv & 255u), (float)((cv >> 8) & 255u),
                       (float)((cv >> 16) & 255u), (float)(cv >> 24)};
#pragma unroll
        for (int e = 0; e < 4; e++) {
            float u   = fmaf(xs[e], istd, nm);
            float uc  = fminf(3.f, fmaxf(-3.f, u));
            float k0f = rintf(uc);               // v_rndne, exact int
            float v   = u - k0f;
            float p   = C1 * v;
            float a0  = p * v;                   // C1 v^2        (<= 0)
            float ac  = a0 + C1;
            float am  = fmaf(p,  2.f, ac);       // C1 (v+1)^2    (<= 0)
            float ap  = fmaf(p, -2.f, ac);       // C1 (v-1)^2    (<= 0)
            float t0  = cf[e] * exp2_raw(a0);    // bin k0
            float tm  = cf[e] * exp2_raw(am);    // bin k0-1
            float tp  = cf[e] * exp2_raw(ap);    // bin k0+1
            int   qi  = (int)k0f;                // -3..3
            unsigned vaddr = Bcol + ((unsigned)qi << 10);  // &hist[qi+3][t]
            // native LDS float atomic add: fire-and-forget, in-order pipe,
            // thread-private column -> race-free
            asm volatile("ds_add_f32 %0, %1"             :: "v"(vaddr), "v"(tm));
            asm volatile("ds_add_f32 %0, %1 offset:1024" :: "v"(vaddr), "v"(t0));
            asm volatile("ds_add_f32 %0, %1 offset:2048" :: "v"(vaddr), "v"(tp));
        }
    }
    __syncthreads();   // waitcnt lgkmcnt(0) + barrier: all ds_adds landed

    // bin j lives at slot j+1; slots 0 and 8 are discards
    float acc[7];
#pragma unroll
    for (int j = 0; j < 7; j++) acc[j] = hist[j + 1][t];

    __shared__ float part[4][7];
#pragma unroll
    for (int j = 0; j < 7; j++) {
        float v = acc[j];
#pragma unroll
        for (int o = 32; o > 0; o >>= 1) v += __shfl_down(v, o);
        if ((t & 63) == 0) part[wid][j] = v;
    }
    __syncthreads();

    if (t == 0) {
        // target: exp(-0.5 k^2)/Z (1/sqrt(2 pi var) cancels in normalization)
        double e[7], z = 0.0;
#pragma unroll
        for (int k = -3; k <= 3; k++) { e[k + 3] = exp(-0.5 * (double)(k * k)); z += e[k + 3]; }

        float hist7[7], S = 0.f;
#pragma unroll
        for (int j = 0; j < 7; j++) {
            hist7[j] = part[0][j] + part[1][j] + part[2][j] + part[3][j];
            S += hist7[j];
        }
        float Ss = fmaxf(S, 1e-30f);
        float ps = 0.f;
#pragma unroll
        for (int j = 0; j < 7; j++) {
            float dd = fabsf(hist7[j] / Ss - (float)(e[j] / z));
            ps += (dd < 1.f) ? 0.5f * dd * dd : (dd - 0.5f);
        }
        atomicAdd(psum, ps);        // raw partial; scaled once in K3
    }
}

// ---------------------------------------------------------------------------
// K3: finalize. A = #active classes; out = psum / (448 * A). Writes out
// absolutely (harness-poisoned d_out needs no pre-zero).
// ---------------------------------------------------------------------------
__global__ __launch_bounds__(64) void hl_final_kernel(
    const float* __restrict__ psum, const int* __restrict__ ncls,
    float* __restrict__ out)
{
    if (threadIdx.x == 0) {
        int A = 0;
#pragma unroll
        for (int i = 0; i < NCLS; i++) A += (ncls[i] >= 1000) ? 1 : 0;
        out[0] = (A > 0) ? psum[0] / (448.0f * (float)A) : 0.0f;
    }
}

// ---------------------------------------------------------------------------
extern "C" void kernel_launch(void* const* d_in, const int* in_sizes, int n_in,
                              void* d_out, int out_size, void* d_ws, size_t ws_size,
                              hipStream_t stream)
{
    const float* feature = (const float*)d_in[0];   // [1,64,128,128] fp32
    const int*   label   = (const int*)d_in[1];     // [1,1,512,512]  int32
    float*       out     = (float*)d_out;           // scalar fp32

    char* ws = (char*)d_ws;
    unsigned char* cnt  = (unsigned char*)(ws);      // 311296 B
    int*           ncls = (int*)(ws + 311296);       // 76 B
    float*         psum = (float*)(ws + 311424);     // 4 B

    hl_count_kernel<<<SRC / 256, 256, 0, stream>>>(label, cnt, psum);
    hl_fused_kernel<<<NPAIR, 256, 0, stream>>>(feature, cnt, ncls, psum);
    hl_final_kernel<<<1, 64, 0, stream>>>(psum, ncls, out);
}

// Round 20
// 90.603 us; speedup vs baseline: 4.2233x; 4.2233x over previous
//
#include <hip/hip_runtime.h>

// Problem constants
#define SRC    16384     // 128*128 source pixels
#define DCH    64        // channels
#define NCLS   19        // classes
#define NPAIR  (NCLS*DCH)// 1216 (c,d) pairs

// Bare v_exp_f32 via inline asm (proven). Args always <= 0 here;
// flush-to-zero underflow matches reference f32 exp behavior.
__device__ __forceinline__ float exp2_raw(float x)
{
    float r;
    asm("v_exp_f32 %0, %1" : "=v"(r) : "v"(x));
    return r;
}

// ---------------------------------------------------------------------------
// K1: per-source-pixel class counts (proven). Also zeroes psum.
// ---------------------------------------------------------------------------
__global__ __launch_bounds__(256) void hl_count_kernel(
    const int* __restrict__ label, unsigned char* __restrict__ cnt,
    float* __restrict__ psum)
{
    if (blockIdx.x == 0 && threadIdx.x == 0) psum[0] = 0.f;
    int s  = blockIdx.x * 256 + threadIdx.x;   // 64 blocks x 256 = 16384
    int sy = s >> 7, sx = s & 127;
    const int4* lab4 = (const int4*)label;
    int l[16];
#pragma unroll
    for (int r = 0; r < 4; r++) {
        int4 v = lab4[(4 * sy + r) * 128 + sx];
        l[4 * r + 0] = v.x; l[4 * r + 1] = v.y;
        l[4 * r + 2] = v.z; l[4 * r + 3] = v.w;
    }
#pragma unroll
    for (int c = 0; c < NCLS; c++) {
        int cc = 0;
#pragma unroll
        for (int j = 0; j < 16; j++) cc += (l[j] == c) ? 1 : 0;
        cnt[c * SRC + s] = (unsigned char)cc;
    }
}

// ---------------------------------------------------------------------------
// K2: fused moments + KDE -- the R0 session-proven structure, with ONE
// change: __launch_bounds__(256, 8).
//
// R17 closed the scatter ledger (all per-element times):
//   7-exp register   = 43.8us  <- optimum; scatter-free
//   3-exp LDS RMW    = 44.5us  (15 LDS-pipe ops ate the savings)
//   3-exp cndmask    = 60.1us  (VALU-issue-bound, 74% VALUBusy)
//   3-exp ds_add_f32 = 328us   (LDS atomics are PER-LANE serialized ~3.4cy)
// Per-element instruction count is at its practical floor; the 2.7x gap to
// the issue-rate model (~128 cyc/wave-el vs ~300 measured) is unhidden
// latency at 4 blocks/CU occupancy + the 192-block dispatch tail.
//
// Fix: launch_bounds(256,8) -> 64-VGPR budget (R3's hl_kde measured exactly
// 64 VGPR for this loop) -> 8 blocks/CU -> all 1216 blocks resident in one
// scheduling wave (<= 2048 slots): no tail, 2x waves for latency hiding.
// Inner loop: k^2-CSE 7-exp form, HW-ref-checked absmax 0.0 (R2/R3).
// ---------------------------------------------------------------------------
__global__ __launch_bounds__(256, 8) void hl_fused_kernel(
    const float* __restrict__ feature, const unsigned char* __restrict__ cnt,
    int* __restrict__ ncls, float* __restrict__ psum)
{
    int w = blockIdx.x;             // pair 0..1215
    int c = w >> 6, d = w & 63;
    int t = threadIdx.x;
    int wid = t >> 6;

    const float4*       fp4 = (const float4*)(feature + d * SRC);
    const unsigned int* cpu = (const unsigned int*)(cnt + c * SRC);

    // ---- Pass 1: moments (proven) -----------------------------------------
    float f1 = 0.f, f2 = 0.f;
    int   nc = 0;
#pragma unroll 4
    for (int i = 0; i < 16; i++) {
        int g = i * 256 + t;        // 4096 float4-groups (= 4096 uint groups)
        float4       x  = fp4[g];
        unsigned int cv = cpu[g];
        float xs[4] = {x.x, x.y, x.z, x.w};
        float cf[4] = {(float)(cv & 255u), (float)((cv >> 8) & 255u),
                       (float)((cv >> 16) & 255u), (float)(cv >> 24)};
#pragma unroll
        for (int e = 0; e < 4; e++) {
            float wx = cf[e] * xs[e];
            f1 += wx;
            f2 = fmaf(wx, xs[e], f2);
        }
        nc += (cv & 255u) + ((cv >> 8) & 255u) + ((cv >> 16) & 255u) + (cv >> 24);
    }
    double s1 = (double)f1, s2 = (double)f2;
#pragma unroll
    for (int o = 32; o > 0; o >>= 1) {
        s1 += __shfl_down(s1, o);
        s2 += __shfl_down(s2, o);
        nc += __shfl_down(nc, o);
    }
    __shared__ double ps1[4], ps2[4];
    __shared__ int    pn[4];
    __shared__ float  sh_mu, sh_istd;
    __shared__ int    sh_act;
    if ((t & 63) == 0) { ps1[wid] = s1; ps2[wid] = s2; pn[wid] = nc; }
    __syncthreads();
    if (t == 0) {
        double a = ps1[0] + ps1[1] + ps1[2] + ps1[3];
        double b = ps2[0] + ps2[1] + ps2[2] + ps2[3];
        int    n = pn[0] + pn[1] + pn[2] + pn[3];
        double nsafe = (n > 0) ? (double)n : 1.0;
        double mu  = a / nsafe;
        double var = (b - 2.0 * mu * a + mu * mu * (double)n) / nsafe + 1e-10;
        sh_mu   = (float)mu;
        sh_istd = (float)(1.0 / sqrt(var));
        sh_act  = (n >= 1000);
        if (d == 0) ncls[c] = n;    // plain store; consumed only by K3
    }
    __syncthreads();
    if (!sh_act) return;            // inactive class: contributes 0
    float istd = sh_istd;
    float nm   = -sh_mu * istd;     // u = fma(x, istd, nm)

    // ---- Pass 2: KDE, 7-exp k^2-CSE form (data L1/L2-hot from pass 1) -----
    const float C1 = -18.033688011112042f;   // -12.5 * log2(e)
    float acc[7] = {0.f, 0.f, 0.f, 0.f, 0.f, 0.f, 0.f};

#pragma unroll 2
    for (int i = 0; i < 16; i++) {
        int g = i * 256 + t;
        float4       x  = fp4[g];
        unsigned int cv = cpu[g];
        float xs[4] = {x.x, x.y, x.z, x.w};
        float cf[4] = {(float)(cv & 255u), (float)((cv >> 8) & 255u),
                       (float)((cv >> 16) & 255u), (float)(cv >> 24)};
#pragma unroll
        for (int e = 0; e < 4; e++) {
            float u  = fmaf(xs[e], istd, nm);
            float p  = C1 * u;
            float q  = p * u;                    // C1*u^2
            float t1 = q + C1;                   // + C1*1
            float t4 = q + 4.f * C1;             // + C1*4
            float t9 = q + 9.f * C1;             // + C1*9
            acc[0] = fmaf(cf[e], exp2_raw(fmaf(p,  6.f, t9)), acc[0]); // k=-3
            acc[1] = fmaf(cf[e], exp2_raw(fmaf(p,  4.f, t4)), acc[1]); // k=-2
            acc[2] = fmaf(cf[e], exp2_raw(fmaf(p,  2.f, t1)), acc[2]); // k=-1
            acc[3] = fmaf(cf[e], exp2_raw(q),                 acc[3]); // k= 0
            acc[4] = fmaf(cf[e], exp2_raw(fmaf(p, -2.f, t1)), acc[4]); // k=+1
            acc[5] = fmaf(cf[e], exp2_raw(fmaf(p, -4.f, t4)), acc[5]); // k=+2
            acc[6] = fmaf(cf[e], exp2_raw(fmaf(p, -6.f, t9)), acc[6]); // k=+3
        }
    }

    __shared__ float part[4][7];
#pragma unroll
    for (int j = 0; j < 7; j++) {
        float v = acc[j];
#pragma unroll
        for (int o = 32; o > 0; o >>= 1) v += __shfl_down(v, o);
        if ((t & 63) == 0) part[wid][j] = v;
    }
    __syncthreads();

    if (t == 0) {
        // target: exp(-0.5 k^2)/Z (1/sqrt(2 pi var) cancels in normalization)
        double e[7], z = 0.0;
#pragma unroll
        for (int k = -3; k <= 3; k++) { e[k + 3] = exp(-0.5 * (double)(k * k)); z += e[k + 3]; }

        float hist7[7], S = 0.f;
#pragma unroll
        for (int j = 0; j < 7; j++) {
            hist7[j] = part[0][j] + part[1][j] + part[2][j] + part[3][j];
            S += hist7[j];
        }
        float Ss = fmaxf(S, 1e-30f);
        float ps = 0.f;
#pragma unroll
        for (int j = 0; j < 7; j++) {
            float dd = fabsf(hist7[j] / Ss - (float)(e[j] / z));
            ps += (dd < 1.f) ? 0.5f * dd * dd : (dd - 0.5f);
        }
        atomicAdd(psum, ps);        // raw partial; scaled once in K3
    }
}

// ---------------------------------------------------------------------------
// K3: finalize. A = #active classes; out = psum / (448 * A). Writes out
// absolutely (harness-poisoned d_out needs no pre-zero).
// ---------------------------------------------------------------------------
__global__ __launch_bounds__(64) void hl_final_kernel(
    const float* __restrict__ psum, const int* __restrict__ ncls,
    float* __restrict__ out)
{
    if (threadIdx.x == 0) {
        int A = 0;
#pragma unroll
        for (int i = 0; i < NCLS; i++) A += (ncls[i] >= 1000) ? 1 : 0;
        out[0] = (A > 0) ? psum[0] / (448.0f * (float)A) : 0.0f;
    }
}

// ---------------------------------------------------------------------------
extern "C" void kernel_launch(void* const* d_in, const int* in_sizes, int n_in,
                              void* d_out, int out_size, void* d_ws, size_t ws_size,
                              hipStream_t stream)
{
    const float* feature = (const float*)d_in[0];   // [1,64,128,128] fp32
    const int*   label   = (const int*)d_in[1];     // [1,1,512,512]  int32
    float*       out     = (float*)d_out;           // scalar fp32

    char* ws = (char*)d_ws;
    unsigned char* cnt  = (unsigned char*)(ws);      // 311296 B
    int*           ncls = (int*)(ws + 311296);       // 76 B
    float*         psum = (float*)(ws + 311424);     // 4 B

    hl_count_kernel<<<SRC / 256, 256, 0, stream>>>(label, cnt, psum);
    hl_fused_kernel<<<NPAIR, 256, 0, stream>>>(feature, cnt, ncls, psum);
    hl_final_kernel<<<1, 64, 0, stream>>>(psum, ncls, out);
}